// Round 5
// baseline (143.749 us; speedup 1.0000x reference)
//
#include <hip/hip_runtime.h>
#include <hip/hip_bf16.h>

// out = (Q K^T * SCALE) @ V  ==  Q @ (SCALE * K^T V)   (softmax discarded in ref)
// B=32, T=2048, E=1024, H=64.  M = B*T = 65536.
// Chain: k_wt (W transpose->bf16), k_qkv (QKV proj + fused per-block K^T V
// partials), k_red (reduce partials -> KtV^T bf16), k_out (Q @ KtV).

using bf16x8 = __attribute__((ext_vector_type(8))) short;
using f32x4  = __attribute__((ext_vector_type(4))) float;
using u32x4  = __attribute__((ext_vector_type(4))) unsigned int;
using u32x2  = __attribute__((ext_vector_type(2))) unsigned int;
using u16    = unsigned short;

__device__ __forceinline__ u16 f2bf(float f) {
    unsigned u = __builtin_bit_cast(unsigned, f);
    u += 0x7fffu + ((u >> 16) & 1u);          // RNE
    return (u16)(u >> 16);
}

#define G2L16(g, l) __builtin_amdgcn_global_load_lds(                         \
    (const __attribute__((address_space(1))) void*)(g),                       \
    (__attribute__((address_space(3))) void*)(l), 16, 0, 0)

// ---------------- k_wt: WT[n][e] = W*[e][n] as bf16 (LDS transpose) ----------------
__global__ __launch_bounds__(256) void k_wt(const float* __restrict__ Wq,
                                            const float* __restrict__ Wk,
                                            const float* __restrict__ Wv,
                                            u16* __restrict__ WT) {
    __shared__ float Wl[64][68];
    const int seg = blockIdx.x >> 4, chunk = blockIdx.x & 15;   // 48 blocks
    const float* W = (seg == 0) ? Wq : (seg == 1) ? Wk : Wv;
    const int e0 = chunk * 64;
    const int tid = threadIdx.x;
    const int lr = tid >> 4, lc = (tid & 15) * 4;
#pragma unroll
    for (int p = 0; p < 4; ++p)
        *(f32x4*)&Wl[lr + p * 16][lc] = *(const f32x4*)(W + (size_t)(e0 + lr + p * 16) * 64 + lc);
    __syncthreads();
    const int c = tid >> 2, eb = (tid & 3) * 16;
    u32x4 o0, o1;
#pragma unroll
    for (int q = 0; q < 4; ++q)
        o0[q] = (unsigned)f2bf(Wl[eb + 2 * q][c]) | ((unsigned)f2bf(Wl[eb + 2 * q + 1][c]) << 16);
#pragma unroll
    for (int q = 0; q < 4; ++q)
        o1[q] = (unsigned)f2bf(Wl[eb + 8 + 2 * q][c]) | ((unsigned)f2bf(Wl[eb + 9 + 2 * q][c]) << 16);
    u16* dst = WT + (size_t)(seg * 64 + c) * 1024 + e0 + eb;
    *(u32x4*)dst = o0;
    *(u32x4*)(dst + 8) = o1;
}

// ---------------- k_qkv: Q = x@Wq+bq (bf16 out) + fused partial K^T V ----------------
// 512 thr (8 waves, 4M x 2N), M-tile 128, N=192, BK=64, 16 chunks.
// x: reg-staged (4 dwordx4/thread) -> bf16 LDS [128][64] dbuf 2*16KB, swz ^((r&7)<<4).
// WT: G2L16 [192][64] dbuf 2*24KB @32768, source pre-swizzled.  LDS 80KB -> 2 blk/CU.
// vmcnt ledger at phase-k wait (issue order: W(k)|x(k+1) in k-1, W(k+1)|x(k+2) in k):
//   keep newest 7 = W(k+1).3 + x(k+2).4  ->  vmcnt(7);  k==15 -> vmcnt(0).
__global__ __launch_bounds__(512, 4) void k_qkv(const float* __restrict__ x,
                                                const u16* __restrict__ WT,
                                                const float* __restrict__ bq,
                                                const float* __restrict__ bk,
                                                const float* __restrict__ bv,
                                                u16* __restrict__ Qb,
                                                float* __restrict__ part) {
    __shared__ __align__(16) char lds[81920];
    const int tid  = threadIdx.x;
    const int wave = tid >> 6, lane = tid & 63;
    const int wr = wave >> 1, wc = wave & 1;      // 4M x 2N wave grid
    const size_t row0 = (size_t)blockIdx.x * 128;

    // x reg-stage geometry: row xr (4 thr/row), 16 f32 (64 B) per thread
    const int xr = tid >> 2, xc4 = tid & 3;
    const float* const xp = x + (row0 + xr) * 1024 + xc4 * 16;
    const int xw_b0 = (xr * 128 + xc4 * 32) ^ ((xr & 7) << 4);
    const int xw_b1 = (xr * 128 + xc4 * 32 + 16) ^ ((xr & 7) << 4);

    // WT staging (pre-swizzled source, linear LDS dest)
    size_t wsrc[3]; int wdstl[3];
#pragma unroll
    for (int j = 0; j < 3; ++j) {
        const int n  = (tid >> 3) + j * 64;
        const int cb = ((tid & 7) * 16) ^ ((n & 7) << 4);
        wsrc[j] = (size_t)n * 1024 + (cb >> 1);
        wdstl[j] = j * 8192 + wave * 1024;
    }

    f32x4 acc[2][6];
#pragma unroll
    for (int m = 0; m < 2; ++m)
#pragma unroll
        for (int n = 0; n < 6; ++n)
#pragma unroll
            for (int r = 0; r < 4; ++r) acc[m][n][r] = 0.0f;

    f32x4 rA[4], rB[4];

#define WRITE_X(BUF, R)                                                       \
    {                                                                         \
        char* const xbw_ = lds + (BUF) * 16384;                               \
        u32x4 p0_, p1_;                                                       \
        p0_[0] = (unsigned)f2bf(R[0][0]) | ((unsigned)f2bf(R[0][1]) << 16);   \
        p0_[1] = (unsigned)f2bf(R[0][2]) | ((unsigned)f2bf(R[0][3]) << 16);   \
        p0_[2] = (unsigned)f2bf(R[1][0]) | ((unsigned)f2bf(R[1][1]) << 16);   \
        p0_[3] = (unsigned)f2bf(R[1][2]) | ((unsigned)f2bf(R[1][3]) << 16);   \
        p1_[0] = (unsigned)f2bf(R[2][0]) | ((unsigned)f2bf(R[2][1]) << 16);   \
        p1_[1] = (unsigned)f2bf(R[2][2]) | ((unsigned)f2bf(R[2][3]) << 16);   \
        p1_[2] = (unsigned)f2bf(R[3][0]) | ((unsigned)f2bf(R[3][1]) << 16);   \
        p1_[3] = (unsigned)f2bf(R[3][2]) | ((unsigned)f2bf(R[3][3]) << 16);   \
        *(u32x4*)(xbw_ + xw_b0) = p0_;                                        \
        *(u32x4*)(xbw_ + xw_b1) = p1_;                                        \
    }

#define COMPUTE(BUF)                                                          \
    {                                                                         \
        const char* const xb_ = lds + (BUF) * 16384;                          \
        const char* const wb_ = lds + 32768 + (BUF) * 24576;                  \
        _Pragma("unroll")                                                     \
        for (int ks = 0; ks < 2; ++ks) {                                      \
            bf16x8 af[2];                                                     \
            _Pragma("unroll")                                                 \
            for (int m = 0; m < 2; ++m) {                                     \
                const int r_ = wr * 32 + m * 16 + (lane & 15);                \
                af[m] = *(const bf16x8*)(xb_ +                                \
                    ((r_ * 128 + ks * 64 + (lane >> 4) * 16) ^ ((r_ & 7) << 4))); \
            }                                                                 \
            _Pragma("unroll")                                                 \
            for (int n = 0; n < 6; ++n) {                                     \
                const int nn_ = wc * 96 + n * 16 + (lane & 15);               \
                const bf16x8 bfr_ = *(const bf16x8*)(wb_ +                    \
                    ((nn_ * 128 + ks * 64 + (lane >> 4) * 16) ^ ((nn_ & 7) << 4))); \
                acc[0][n] = __builtin_amdgcn_mfma_f32_16x16x32_bf16(af[0], bfr_, acc[0][n], 0, 0, 0); \
                acc[1][n] = __builtin_amdgcn_mfma_f32_16x16x32_bf16(af[1], bfr_, acc[1][n], 0, 0, 0); \
            }                                                                 \
        }                                                                     \
    }

#define PHASE(K, RN, RF)                                                      \
    {                                                                         \
        const int k_ = (K);                                                   \
        if (k_ < 15) {                                                        \
            char* const wbb_ = lds + 32768 + ((k_ + 1) & 1) * 24576;          \
            const int k0_ = (k_ + 1) * 64;                                    \
            _Pragma("unroll")                                                 \
            for (int j = 0; j < 3; ++j) G2L16(WT + wsrc[j] + k0_, wbb_ + wdstl[j]); \
        }                                                                     \
        if (k_ < 14) {                                                        \
            _Pragma("unroll")                                                 \
            for (int q = 0; q < 4; ++q)                                       \
                RF[q] = *(const f32x4*)(xp + (k_ + 2) * 64 + q * 4);          \
        }                                                                     \
        asm volatile("" ::: "memory");                                        \
        if (k_ < 15) asm volatile("s_waitcnt vmcnt(7)" ::: "memory");         \
        else         asm volatile("s_waitcnt vmcnt(0)" ::: "memory");         \
        __builtin_amdgcn_s_barrier();                                         \
        __builtin_amdgcn_sched_barrier(0);                                    \
        if (k_ < 15) WRITE_X((k_ + 1) & 1, RN);                               \
        COMPUTE(k_ & 1);                                                      \
        asm volatile("s_waitcnt lgkmcnt(0)" ::: "memory");                    \
        __builtin_amdgcn_sched_barrier(0);                                    \
        __builtin_amdgcn_s_barrier();                                         \
    }

    // ---- prologue: x(0)->rA, W(0)->wbuf0, x(1)->rB; write x(0)->xbuf0 ----
#pragma unroll
    for (int q = 0; q < 4; ++q) rA[q] = *(const f32x4*)(xp + q * 4);
#pragma unroll
    for (int j = 0; j < 3; ++j) G2L16(WT + wsrc[j], lds + 32768 + wdstl[j]);
#pragma unroll
    for (int q = 0; q < 4; ++q) rB[q] = *(const f32x4*)(xp + 64 + q * 4);
    asm volatile("s_waitcnt vmcnt(7)" ::: "memory");   // x(0) landed
    WRITE_X(0, rA);
    asm volatile("s_waitcnt lgkmcnt(0)" ::: "memory");

    // ---- main loop: 16 phases, unroll-2 for static reg names ----
    for (int kk = 0; kk < 16; kk += 2) {
        PHASE(kk,     rB, rA);     // near = x(kk+1) in rB, far -> rA = x(kk+2)
        PHASE(kk + 1, rA, rB);
    }

    // ---- epilogue: Q -> global; K,V -> LDS transposed bf16 tiles (+bias) ----
    // D-layout: col = lane&15, row = (lane>>4)*4 + rr
    u16* const Kt = (u16*)lds;                    // [64][136]  (h_k major, 17408 B)
    u16* const Vt = (u16*)(lds + 20480);          // [64][136]  (h_v major)
#pragma unroll
    for (int n = 0; n < 6; ++n) {
        const int ncol = wc * 96 + n * 16;
        const int seg = ncol >> 6;
        const int col = (ncol & 63) + (lane & 15);
        const float bias = ((seg == 0) ? bq : (seg == 1) ? bk : bv)[col];
#pragma unroll
        for (int m = 0; m < 2; ++m) {
            const int rloc = wr * 32 + m * 16 + ((lane >> 4) << 2);
            if (seg == 0) {
#pragma unroll
                for (int rr = 0; rr < 4; ++rr)
                    Qb[(row0 + rloc + rr) * 64 + col] = f2bf(acc[m][n][rr] + bias);
            } else {
                u16* const T = (seg == 1) ? Kt : Vt;
#pragma unroll
                for (int rr = 0; rr < 4; ++rr)
                    T[col * 136 + rloc + rr] = f2bf(acc[m][n][rr] + bias);
            }
        }
    }
    __syncthreads();

    // ---- fused K^T V partial: D[hv][hk] = sum_{128 rows} V[row][hv]*K[row][hk] ----
    float* const P = part + (size_t)blockIdx.x * 4096;
#pragma unroll
    for (int i = 0; i < 2; ++i) {
        const int f = wave * 2 + i;
        const int m0 = (f & 3) * 16;              // h_v
        const int n0 = (f >> 2) * 16;             // h_k
        f32x4 d;
        d[0] = d[1] = d[2] = d[3] = 0.0f;
#pragma unroll
        for (int ks = 0; ks < 4; ++ks) {
            const bf16x8 a = *(const bf16x8*)(Vt + (m0 + (lane & 15)) * 136 + ks * 32 + (lane >> 4) * 8);
            const bf16x8 b = *(const bf16x8*)(Kt + (n0 + (lane & 15)) * 136 + ks * 32 + (lane >> 4) * 8);
            d = __builtin_amdgcn_mfma_f32_16x16x32_bf16(a, b, d, 0, 0, 0);
        }
#pragma unroll
        for (int rr = 0; rr < 4; ++rr)
            P[(m0 + (lane >> 4) * 4 + rr) * 64 + n0 + (lane & 15)] = d[rr];
    }
#undef PHASE
#undef COMPUTE
#undef WRITE_X
}

// ---------------- k_red: KtVT[b][o] = SCALE * sum_c part[b*16+c][o], bf16 ----------------
__global__ __launch_bounds__(256) void k_red(const float* __restrict__ part,
                                             u16* __restrict__ KtVT) {
    const int b = blockIdx.x >> 2;
    const int o0 = (blockIdx.x & 3) * 1024 + threadIdx.x * 4;
    const float* const Pb = part + (size_t)b * 16 * 4096;
    f32x4 s;
    s[0] = s[1] = s[2] = s[3] = 0.0f;
#pragma unroll 8
    for (int c = 0; c < 16; ++c) s += *(const f32x4*)(Pb + c * 4096 + o0);
    s *= 0.125f;                                   // SCALE = 64^-0.5
    u32x2 pk;
    pk[0] = (unsigned)f2bf(s[0]) | ((unsigned)f2bf(s[1]) << 16);
    pk[1] = (unsigned)f2bf(s[2]) | ((unsigned)f2bf(s[3]) << 16);
    *(u32x2*)(KtVT + (size_t)b * 4096 + o0) = pk;
}

// ---------------- k_out: out = Q @ KtV (K=64), fp32 out ----------------
__global__ __launch_bounds__(256) void k_out(const u16* __restrict__ Qb,
                                             const u16* __restrict__ KtVT,
                                             float* __restrict__ out) {
    const int tid = threadIdx.x;
    const int wave = tid >> 6, lane = tid & 63;
    const size_t m0 = (size_t)blockIdx.x * 64 + wave * 16;
    const int b = blockIdx.x >> 5;            // 32 blocks per batch
    const u16* const Bp = KtVT + (size_t)b * 4096;

    bf16x8 bfrag[2][4];
#pragma unroll
    for (int ks = 0; ks < 2; ++ks)
#pragma unroll
        for (int nt = 0; nt < 4; ++nt)
            bfrag[ks][nt] = *(const bf16x8*)(Bp + (nt * 16 + (lane & 15)) * 64 + ks * 32 + (lane >> 4) * 8);

    f32x4 acc[4];
#pragma unroll
    for (int nt = 0; nt < 4; ++nt)
#pragma unroll
        for (int r = 0; r < 4; ++r) acc[nt][r] = 0.0f;

#pragma unroll
    for (int ks = 0; ks < 2; ++ks) {
        const bf16x8 a = *(const bf16x8*)(Qb + (m0 + (lane & 15)) * 64 + ks * 32 + (lane >> 4) * 8);
#pragma unroll
        for (int nt = 0; nt < 4; ++nt)
            acc[nt] = __builtin_amdgcn_mfma_f32_16x16x32_bf16(a, bfrag[ks][nt], acc[nt], 0, 0, 0);
    }
#pragma unroll
    for (int nt = 0; nt < 4; ++nt)
#pragma unroll
        for (int rr = 0; rr < 4; ++rr)
            out[(m0 + (lane >> 4) * 4 + rr) * 64 + nt * 16 + (lane & 15)] = acc[nt][rr];
}

extern "C" void kernel_launch(void* const* d_in, const int* in_sizes, int n_in,
                              void* d_out, int out_size, void* d_ws, size_t ws_size,
                              hipStream_t stream) {
    (void)in_sizes; (void)n_in; (void)out_size; (void)ws_size;
    const float* x  = (const float*)d_in[0];
    const float* Wq = (const float*)d_in[1];
    const float* bq = (const float*)d_in[2];
    const float* Wk = (const float*)d_in[3];
    const float* bk = (const float*)d_in[4];
    const float* Wv = (const float*)d_in[5];
    const float* bv = (const float*)d_in[6];
    float* out = (float*)d_out;

    char* ws = (char*)d_ws;                       // layout (~16.6 MB total):
    u16*  WT   = (u16*)(ws);                      // 0x0000000: 384 KB  WT bf16 [192][1024]
    u16*  Qb   = (u16*)(ws + 0x60000);            // 0x0060000: 8 MB    Q bf16 [65536][64]
    float* part= (float*)(ws + 0x860000);         // 0x0860000: 8 MB    partials [512][64][64] f32
    u16*  KtVT = (u16*)(ws + 0x1060000);          // 0x1060000: 256 KB  KtV^T bf16 [32][64][64]

    k_wt <<<48,   256, 0, stream>>>(Wq, Wk, Wv, WT);
    k_qkv<<<512,  512, 0, stream>>>(x, WT, bq, bk, bv, Qb, part);
    k_red<<<128,  256, 0, stream>>>(part, KtVT);
    k_out<<<1024, 256, 0, stream>>>(Qb, KtVT, out);
}